// Round 11
// baseline (183.227 us; speedup 1.0000x reference)
//
#include <hip/hip_runtime.h>

typedef unsigned short ushort_t;
typedef __bf16 bf16x8 __attribute__((ext_vector_type(8)));
typedef float f32x4 __attribute__((ext_vector_type(4)));
typedef float f32x16 __attribute__((ext_vector_type(16)));

#define DEVI __device__ __forceinline__

constexpr int BSZ = 4;     // batch
constexpr int MDIM = 190;  // axial dim
constexpr int TDIM = 512;  // seq
constexpr int CDIM = 64;   // channels

DEVI ushort_t f2bf(float f) {
    union { float f; unsigned int u; } v; v.f = f;
    unsigned int u = v.u;
    u += 0x7FFFu + ((u >> 16) & 1u);   // round-to-nearest-even
    return (ushort_t)(u >> 16);
}

DEVI void gload16(ushort_t* ldsBase, const ushort_t* g) {
    __builtin_amdgcn_global_load_lds(
        (const __attribute__((address_space(1))) unsigned int*)g,
        (__attribute__((address_space(3))) unsigned int*)ldsBase, 16, 0, 0);
}

// ---------------------------------------------------------------- K1: fused v-projection + xsum partials
// vf[b][mblk48][n][ks32][cg2][lane64][elem8]: col = cg*32 + l31 -> mrel = cg*2 + (l31>>4), d = l31&15;
// k = ks*16 + (lane>>5)*8 + j.
__global__ __launch_bounds__(256, 4) void k_vproj(const float* __restrict__ x,
                                                  const float* __restrict__ Wv,
                                                  const float* __restrict__ bv,
                                                  ushort_t* __restrict__ vf,
                                                  float* __restrict__ xsp) {
    __shared__ __align__(16) ushort_t xbf[64 * 72];
    __shared__ __align__(16) ushort_t WvT[64 * 72];
    __shared__ __align__(16) ushort_t vst[64 * 72];

    int tid = threadIdx.x;
    int bid = blockIdx.x;            // 512 = 4b * 8tt * 16mg
    int mg = bid & 15;
    int tt = (bid >> 4) & 7;
    int b = bid >> 7;
    int t0 = tt * 64;
    int mbase = mg * 12;
    int cnt = (mbase + 12 <= MDIM) ? 12 : (MDIM - mbase);   // 12 or 10

    int w = tid >> 6, lane = tid & 63;
    int la = lane & 15, lb = lane >> 4;
    int r = tid >> 2, seg = tid & 3;

    int chunk = tid >> 3, u = tid & 7;
    int ksr = chunk >> 3;
    int nn2 = (chunk >> 1) & 3;
    int lhi2 = chunk & 1;
    int d0 = u * 2;

#pragma unroll
    for (int rep = 0; rep < 16; ++rep) {
        int j = rep * 256 + tid;
        int ci = j >> 6, co = j & 63;
        WvT[co * 72 + ci] = f2bf(Wv[j]);
    }
    float bvv[4];
#pragma unroll
    for (int cf = 0; cf < 4; ++cf) bvv[cf] = bv[16 * cf + la];

    float xacc[16];
#pragma unroll
    for (int u2 = 0; u2 < 16; ++u2) xacc[u2] = 0.f;

    const size_t mstride = (size_t)TDIM * CDIM;  // 32768
    size_t xaddr = ((size_t)(b * MDIM + mbase) * TDIM + t0 + r) * CDIM + seg * 16;

    float4 xv[4];
#pragma unroll
    for (int u2 = 0; u2 < 4; ++u2) xv[u2] = *(const float4*)(x + xaddr + u2 * 4);

    f32x4 zz = {0.f, 0.f, 0.f, 0.f};

    for (int i = 0; i < cnt; ++i) {
#pragma unroll
        for (int u2 = 0; u2 < 4; ++u2) {
            xacc[u2 * 4 + 0] += xv[u2].x;
            xacc[u2 * 4 + 1] += xv[u2].y;
            xacc[u2 * 4 + 2] += xv[u2].z;
            xacc[u2 * 4 + 3] += xv[u2].w;
            ushort4 h;
            h.x = f2bf(xv[u2].x); h.y = f2bf(xv[u2].y);
            h.z = f2bf(xv[u2].z); h.w = f2bf(xv[u2].w);
            *(ushort4*)&xbf[r * 72 + seg * 16 + u2 * 4] = h;
        }
        __syncthreads();

        int inext = (i + 1 < cnt) ? (i + 1) : i;
        size_t xaddr2 = xaddr + (size_t)(inext - i) * mstride;
        float4 xv2[4];
#pragma unroll
        for (int u2 = 0; u2 < 4; ++u2) xv2[u2] = *(const float4*)(x + xaddr2 + u2 * 4);

        f32x4 acc2[4];
#pragma unroll
        for (int cf = 0; cf < 4; ++cf) acc2[cf] = zz;
#pragma unroll
        for (int ks = 0; ks < 2; ++ks) {
            bf16x8 aa = *(const bf16x8*)&xbf[(w * 16 + la) * 72 + ks * 32 + lb * 8];
#pragma unroll
            for (int cf = 0; cf < 4; ++cf) {
                bf16x8 bb = *(const bf16x8*)&WvT[(16 * cf + la) * 72 + ks * 32 + lb * 8];
                acc2[cf] = __builtin_amdgcn_mfma_f32_16x16x32_bf16(aa, bb, acc2[cf], 0, 0, 0);
            }
        }
#pragma unroll
        for (int cf = 0; cf < 4; ++cf) {
            ushort4 h;
            h.x = f2bf(acc2[cf][0] + bvv[cf]);
            h.y = f2bf(acc2[cf][1] + bvv[cf]);
            h.z = f2bf(acc2[cf][2] + bvv[cf]);
            h.w = f2bf(acc2[cf][3] + bvv[cf]);
            *(ushort4*)&vst[(16 * cf + la) * 72 + w * 16 + lb * 4] = h;   // vst[c][t_rel]
        }
        __syncthreads();

        int m = mbase + i;
        int mblk = m >> 2, mrel = m & 3;
        int cg = mrel >> 1, half = mrel & 1;
        size_t vfbase = ((((size_t)(b * 48 + mblk) * 4 + nn2) * 32 + (tt * 4 + ksr)) * 2 + cg) * 512
                      + (size_t)(lhi2 * 32 + half * 16 + d0) * 8;
        uint4 v0 = *(const uint4*)&vst[(nn2 * 16 + d0) * 72 + ksr * 16 + lhi2 * 8];
        uint4 v1 = *(const uint4*)&vst[(nn2 * 16 + d0 + 1) * 72 + ksr * 16 + lhi2 * 8];
        *(uint4*)(vf + vfbase) = v0;
        *(uint4*)(vf + vfbase + 8) = v1;

#pragma unroll
        for (int u2 = 0; u2 < 4; ++u2) xv[u2] = xv2[u2];
        xaddr = xaddr2;
    }

    if (mg == 15) {
        uint4 z4 = {0u, 0u, 0u, 0u};
#pragma unroll
        for (int pm = 190; pm < 192; ++pm) {
            int mblk = pm >> 2, mrel = pm & 3;
            int cg = mrel >> 1, half = mrel & 1;
            size_t vfbase = ((((size_t)(b * 48 + mblk) * 4 + nn2) * 32 + (tt * 4 + ksr)) * 2 + cg) * 512
                          + (size_t)(lhi2 * 32 + half * 16 + d0) * 8;
            *(uint4*)(vf + vfbase) = z4;
            *(uint4*)(vf + vfbase + 8) = z4;
        }
    }

    size_t sbase = ((size_t)(mg * 4 + b) * TDIM + t0 + r) * CDIM + seg * 16;
#pragma unroll
    for (int u2 = 0; u2 < 4; ++u2) {
        float4 o;
        o.x = xacc[u2 * 4 + 0]; o.y = xacc[u2 * 4 + 1];
        o.z = xacc[u2 * 4 + 2]; o.w = xacc[u2 * 4 + 3];
        *(float4*)(xsp + sbase + u2 * 4) = o;
    }
}

// ---------------------------------------------------------------- K1b: reduce 16 partials -> xsum
__global__ __launch_bounds__(256) void k_xsum2(const float* __restrict__ xsp,
                                               float* __restrict__ xsum) {
    int idx = blockIdx.x * 256 + threadIdx.x;   // 131072
    float s = 0.f;
#pragma unroll
    for (int p = 0; p < 16; ++p) s += xsp[(size_t)p * 131072 + idx];
    xsum[idx] = s;
}

// ---------------------------------------------------------------- K2: weights (qt/kt + softmax), frag-order output
// wf[b][n][tq16][ks32][lane64][elem8]: row = tq*32 + l31, k = ks*16 + lhi*8 + j.
__global__ __launch_bounds__(256) void k_weights(const float* __restrict__ xsum,
                                                 const float* __restrict__ Wq,
                                                 const float* __restrict__ bq,
                                                 const float* __restrict__ Wk,
                                                 const float* __restrict__ bk,
                                                 ushort_t* __restrict__ wf,
                                                 float* __restrict__ a_out) {
    __shared__ __align__(16) float kt[512][20];
    __shared__ __align__(16) float qt[32][20];
    __shared__ __align__(16) float xs[64][68];
    __shared__ __align__(16) float wcol[64][16];
    __shared__ float kbias[16], qbias[16];
    __shared__ __align__(16) ushort_t rowbuf[32][520];

    int tid = threadIdx.x;
    int bid = blockIdx.x;        // 256 blocks
    int tcn = bid & 15;          // t-chunk (32 rows) == tq
    int n = (bid >> 4) & 3;
    int b = bid >> 6;
    int t0 = tcn * 32;

    for (int j = tid; j < 1024; j += 256) {
        int c = j >> 4, d = j & 15;
        wcol[c][d] = Wk[c * 64 + n * 16 + d];
    }
    if (tid < 16) kbias[tid] = 190.0f * bk[n * 16 + tid];
    if (tid >= 16 && tid < 32) qbias[tid - 16] = 190.0f * bq[n * 16 + tid - 16];
    __syncthreads();

    for (int ch = 0; ch < 8; ++ch) {
        for (int j = tid; j < 4096; j += 256) {
            int t = j >> 6, c = j & 63;
            xs[t][c] = xsum[((size_t)(b * 512) + (ch * 64 + t)) * 64 + c];
        }
        __syncthreads();
#pragma unroll
        for (int o = 0; o < 4; ++o) {
            int oi = o * 256 + tid;
            int t = oi >> 4, d = oi & 15;
            float s = 0.f;
#pragma unroll
            for (int c = 0; c < 64; ++c) s += xs[t][c] * wcol[c][d];
            kt[ch * 64 + t][d] = s + kbias[d];
        }
        __syncthreads();
    }

    for (int j = tid; j < 1024; j += 256) {
        int c = j >> 4, d = j & 15;
        wcol[c][d] = Wq[c * 64 + n * 16 + d];
    }
    for (int j = tid; j < 2048; j += 256) {
        int t = j >> 6, c = j & 63;
        xs[t][c] = xsum[((size_t)(b * 512) + (t0 + t)) * 64 + c];
    }
    __syncthreads();
#pragma unroll
    for (int o = 0; o < 2; ++o) {
        int oi = o * 256 + tid;
        int t = oi >> 4, d = oi & 15;
        float s = 0.f;
#pragma unroll
        for (int c = 0; c < 64; ++c) s += xs[t][c] * wcol[c][d];
        qt[t][d] = s + qbias[d];
    }
    __syncthreads();

    const float scale = 0.01813692f;  // 1/sqrt(16*190)
    int w = tid >> 6, lane = tid & 63;
    for (int rr = 0; rr < 8; ++rr) {
        int r = w * 8 + rr;
        float qreg[16];
#pragma unroll
        for (int d = 0; d < 16; ++d) qreg[d] = qt[r][d];
        float lv[8];
#pragma unroll
        for (int i = 0; i < 8; ++i) {
            int k = lane + 64 * i;
            const float* kr = &kt[k][0];
            float s = 0.f;
#pragma unroll
            for (int d = 0; d < 16; ++d) s += qreg[d] * kr[d];
            lv[i] = s * scale;
        }
        float mx = lv[0];
#pragma unroll
        for (int i = 1; i < 8; ++i) mx = fmaxf(mx, lv[i]);
#pragma unroll
        for (int off = 32; off >= 1; off >>= 1) mx = fmaxf(mx, __shfl_xor(mx, off));
        float se = 0.f;
#pragma unroll
        for (int i = 0; i < 8; ++i) { lv[i] = __expf(lv[i] - mx); se += lv[i]; }
#pragma unroll
        for (int off = 32; off >= 1; off >>= 1) se += __shfl_xor(se, off);
        float inv = 1.0f / se;

        size_t abase = ((size_t)(n * 512 + (t0 + r))) * 512;
#pragma unroll
        for (int i = 0; i < 8; ++i) {
            float wv = lv[i] * inv;
            rowbuf[r][lane + 64 * i] = f2bf(wv);
            if (b == 0) a_out[abase + lane + 64 * i] = wv;
        }
    }
    __syncthreads();

    size_t wfbase = ((size_t)((b * 4 + n) * 16 + tcn)) * 32 * 512;
#pragma unroll
    for (int p = 0; p < 8; ++p) {
        int id = p * 256 + tid;          // 0..2047
        int ks = id >> 6;
        int lf = id & 63;
        int l31 = lf & 31, lhi = lf >> 5;
        uint4 v = *(const uint4*)&rowbuf[l31][ks * 16 + lhi * 8];
        *(uint4*)(wf + wfbase + (size_t)ks * 512 + lf * 8) = v;
    }
}

// ---------------------------------------------------------------- K4: LDS-resident V att GEMM.
// Block = (b, mq of 4m, th of 256t), 1024 thr = 16 waves = (n, cg, tq).
// V (4m x 64c x 512k) staged once into 64KB LDS arena (4 chunks of 128k).
// W streamed from wf: per-XCD panel (b,th) is 1MB -> L2-pinned via swizzle.
// Epilogue reuses arena: WpT @0, XOR-swizzled attS @4352; 4 passes (cg x t128).
__global__ __launch_bounds__(1024, 4) void k_att(const ushort_t* __restrict__ wf,
                                                 const ushort_t* __restrict__ vf,
                                                 const float* __restrict__ Wp,
                                                 const float* __restrict__ bp,
                                                 float* __restrict__ out) {
    __shared__ __align__(16) ushort_t arena[32768];   // 64 KB exactly

    int tid = threadIdx.x;
    int bid0 = blockIdx.x;                     // 384 = 8 panels * 48 mq
    int bid = (bid0 & 7) * 48 + (bid0 >> 3);   // XCD x owns panel x (one (b,th) pair)
    int mq = bid % 48;
    int pane = bid / 48;                       // 0..7
    int th = pane & 1;
    int b = pane >> 1;

    int wid = tid >> 6, lane = tid & 63;
    int l31 = lane & 31, lhi = lane >> 5;
    int n = wid >> 2;          // head
    int cg = (wid >> 1) & 1;   // m-pair within quad
    int tq = wid & 1;          // 128-t half of block's 256

    // staging constants: unit u = p*1024 + tid, p = n-index
    int ksl0 = (tid >> 7) & 7;
    int cg0 = (tid >> 6) & 1;
    int lane0 = tid & 63;
    unsigned vsrc[4];
#pragma unroll
    for (int p = 0; p < 4; ++p)
        vsrc[p] = (unsigned)(((((b * 48 + mq) * 4 + p) * 32 + ksl0) * 2 + cg0) * 512 + lane0 * 8);
    ushort_t* vdst[4];
#pragma unroll
    for (int p = 0; p < 4; ++p) vdst[p] = arena + (p * 1024 + tid) * 8;

    // A bases: tq16 = th*8 + tq*4 + q
    unsigned abase[4];
#pragma unroll
    for (int q = 0; q < 4; ++q)
        abase[q] = (unsigned)((((b * 4 + n) * 16 + th * 8 + tq * 4 + q) * 32) * 512 + lane * 8);

    // B LDS offset (ushort units): sV[n][ksl][cg][lane][8]
    int boff = ((n * 8) * 2 + cg) * 512 + lane * 8;   // + ksl*1024

    f32x16 acc[4];
#pragma unroll
    for (int q = 0; q < 4; ++q) acc[q] = (f32x16)(0.f);

    // ---- main loop: 4 chunks of 128k
    for (int c = 0; c < 4; ++c) {
        if (c) __syncthreads();                 // everyone done reading previous chunk
#pragma unroll
        for (int p = 0; p < 4; ++p) gload16(vdst[p], vf + vsrc[p] + c * 8192);
        __syncthreads();                        // drains vmcnt: chunk visible
#pragma unroll
        for (int ksl = 0; ksl < 8; ++ksl) {
            int ks = c * 8 + ksl;
            bf16x8 bb = *(const bf16x8*)(arena + boff + ksl * 1024);
#pragma unroll
            for (int q = 0; q < 4; ++q) {
                bf16x8 aa = *(const bf16x8*)(wf + abase[q] + ks * 512);
                acc[q] = __builtin_amdgcn_mfma_f32_32x32x16_bf16(aa, bb, acc[q], 0, 0, 0);
            }
        }
    }

    // ---- epilogue: arena reused. WpT @0 (64x68), attS @4352 (2m x 128t x 64c, XOR-swizzled)
    __syncthreads();
#pragma unroll
    for (int p = 0; p < 4; ++p) {
        int j = p * 1024 + tid;
        int ci = j >> 6, co = j & 63;
        arena[co * 68 + ci] = f2bf(Wp[j]);
    }
    ushort_t* attS = arena + 4352;

    // GEMM2 task decode
    int mloc2 = wid >> 3, rt = (wid >> 1) & 3, cf = wid & 1;
    float bpv = bp[cf * 32 + l31];

#pragma unroll
    for (int pcg = 0; pcg < 2; ++pcg)
#pragma unroll
        for (int pth = 0; pth < 2; ++pth) {
            __syncthreads();
            if (cg == pcg && tq == pth) {
                int mloc = l31 >> 4, d = l31 & 15;
#pragma unroll
                for (int q = 0; q < 4; ++q) {
                    f32x16 a = acc[q];
#pragma unroll
                    for (int r = 0; r < 16; ++r) {
                        int ts = q * 32 + (r & 3) + 8 * (r >> 2) + 4 * lhi;
                        int idx = (((mloc * 128 + ts) * 64) + n * 16 + d) ^ ((ts & 7) << 3);
                        attS[idx] = f2bf(a[r]);
                    }
                }
            }
            __syncthreads();

            f32x16 a2 = (f32x16)(0.f);
#pragma unroll
            for (int kk = 0; kk < 4; ++kk) {
                int aoff = (((mloc2 * 128 + rt * 32 + l31) * 64) + kk * 16 + lhi * 8) ^ ((l31 & 7) << 3);
                bf16x8 aa = *(const bf16x8*)(attS + aoff);
                bf16x8 bb = *(const bf16x8*)(arena + (cf * 32 + l31) * 68 + kk * 16 + lhi * 8);
                a2 = __builtin_amdgcn_mfma_f32_32x32x16_bf16(aa, bb, a2, 0, 0, 0);
            }
            int m = mq * 4 + pcg * 2 + mloc2;
            if (m < 190) {
                size_t obase = ((size_t)(b * 190 + m) * 512 + th * 256 + pth * 128 + rt * 32) * 64;
#pragma unroll
                for (int r = 0; r < 16; ++r) {
                    int trow = (r & 3) + 8 * (r >> 2) + 4 * lhi;
                    out[obase + (size_t)trow * 64 + cf * 32 + l31] = a2[r] + bpv;
                }
            }
        }
}

// ----------------------------------------------------------------
extern "C" void kernel_launch(void* const* d_in, const int* in_sizes, int n_in,
                              void* d_out, int out_size, void* d_ws, size_t ws_size,
                              hipStream_t stream) {
    const float* x  = (const float*)d_in[0];
    const float* Wq = (const float*)d_in[1];
    const float* bq = (const float*)d_in[2];
    const float* Wk = (const float*)d_in[3];
    const float* bk = (const float*)d_in[4];
    const float* Wv = (const float*)d_in[5];
    const float* bv = (const float*)d_in[6];
    const float* Wp = (const float*)d_in[7];
    const float* bp = (const float*)d_in[8];

    float* out = (float*)d_out;
    float* a_out = out + (size_t)BSZ * MDIM * TDIM * CDIM;   // 24903680

    // xsum partials in the out region (8 MB), fully overwritten by k_att later.
    float* xsp = out;

    float* xsum = (float*)d_ws;                                         // 512 KB
    ushort_t* wf = (ushort_t*)((char*)d_ws + 524288);                   // 8.39 MB
    ushort_t* vf = (ushort_t*)((char*)d_ws + 524288 + 8388608);         // 50.33 MB

    k_vproj<<<512, 256, 0, stream>>>(x, Wv, bv, vf, xsp);
    k_xsum2<<<512, 256, 0, stream>>>(xsp, xsum);
    k_weights<<<256, 256, 0, stream>>>(xsum, Wq, bq, Wk, bk, wf, a_out);
    k_att<<<384, 1024, 0, stream>>>(wf, vf, Wp, bp, out);
}

// Round 12
// 140.562 us; speedup vs baseline: 1.3035x; 1.3035x over previous
//
#include <hip/hip_runtime.h>

typedef unsigned short ushort_t;
typedef __bf16 bf16x8 __attribute__((ext_vector_type(8)));
typedef float f32x4 __attribute__((ext_vector_type(4)));
typedef float f32x16 __attribute__((ext_vector_type(16)));

#define DEVI __device__ __forceinline__

constexpr int BSZ = 4;     // batch
constexpr int MDIM = 190;  // axial dim
constexpr int TDIM = 512;  // seq
constexpr int CDIM = 64;   // channels

DEVI ushort_t f2bf(float f) {
    union { float f; unsigned int u; } v; v.f = f;
    unsigned int u = v.u;
    u += 0x7FFFu + ((u >> 16) & 1u);   // round-to-nearest-even
    return (ushort_t)(u >> 16);
}

// ---------------------------------------------------------------- K1: fused v-projection + xsum partials
// vf[b][mblk48][n][ks32][cg2][lane64][elem8]: col = cg*32 + l31 -> mrel = cg*2 + (l31>>4), d = l31&15;
// k = ks*16 + (lane>>5)*8 + j.
__global__ __launch_bounds__(256, 4) void k_vproj(const float* __restrict__ x,
                                                  const float* __restrict__ Wv,
                                                  const float* __restrict__ bv,
                                                  ushort_t* __restrict__ vf,
                                                  float* __restrict__ xsp) {
    __shared__ __align__(16) ushort_t xbf[64 * 72];
    __shared__ __align__(16) ushort_t WvT[64 * 72];
    __shared__ __align__(16) ushort_t vst[64 * 72];

    int tid = threadIdx.x;
    int bid = blockIdx.x;            // 512 = 4b * 8tt * 16mg
    int mg = bid & 15;
    int tt = (bid >> 4) & 7;
    int b = bid >> 7;
    int t0 = tt * 64;
    int mbase = mg * 12;
    int cnt = (mbase + 12 <= MDIM) ? 12 : (MDIM - mbase);   // 12 or 10

    int w = tid >> 6, lane = tid & 63;
    int la = lane & 15, lb = lane >> 4;
    int r = tid >> 2, seg = tid & 3;

    int chunk = tid >> 3, u = tid & 7;
    int ksr = chunk >> 3;
    int nn2 = (chunk >> 1) & 3;
    int lhi2 = chunk & 1;
    int d0 = u * 2;

#pragma unroll
    for (int rep = 0; rep < 16; ++rep) {
        int j = rep * 256 + tid;
        int ci = j >> 6, co = j & 63;
        WvT[co * 72 + ci] = f2bf(Wv[j]);
    }
    float bvv[4];
#pragma unroll
    for (int cf = 0; cf < 4; ++cf) bvv[cf] = bv[16 * cf + la];

    float xacc[16];
#pragma unroll
    for (int u2 = 0; u2 < 16; ++u2) xacc[u2] = 0.f;

    const size_t mstride = (size_t)TDIM * CDIM;  // 32768
    size_t xaddr = ((size_t)(b * MDIM + mbase) * TDIM + t0 + r) * CDIM + seg * 16;

    float4 xv[4];
#pragma unroll
    for (int u2 = 0; u2 < 4; ++u2) xv[u2] = *(const float4*)(x + xaddr + u2 * 4);

    f32x4 zz = {0.f, 0.f, 0.f, 0.f};

    for (int i = 0; i < cnt; ++i) {
#pragma unroll
        for (int u2 = 0; u2 < 4; ++u2) {
            xacc[u2 * 4 + 0] += xv[u2].x;
            xacc[u2 * 4 + 1] += xv[u2].y;
            xacc[u2 * 4 + 2] += xv[u2].z;
            xacc[u2 * 4 + 3] += xv[u2].w;
            ushort4 h;
            h.x = f2bf(xv[u2].x); h.y = f2bf(xv[u2].y);
            h.z = f2bf(xv[u2].z); h.w = f2bf(xv[u2].w);
            *(ushort4*)&xbf[r * 72 + seg * 16 + u2 * 4] = h;
        }
        __syncthreads();

        int inext = (i + 1 < cnt) ? (i + 1) : i;
        size_t xaddr2 = xaddr + (size_t)(inext - i) * mstride;
        float4 xv2[4];
#pragma unroll
        for (int u2 = 0; u2 < 4; ++u2) xv2[u2] = *(const float4*)(x + xaddr2 + u2 * 4);

        f32x4 acc2[4];
#pragma unroll
        for (int cf = 0; cf < 4; ++cf) acc2[cf] = zz;
#pragma unroll
        for (int ks = 0; ks < 2; ++ks) {
            bf16x8 aa = *(const bf16x8*)&xbf[(w * 16 + la) * 72 + ks * 32 + lb * 8];
#pragma unroll
            for (int cf = 0; cf < 4; ++cf) {
                bf16x8 bb = *(const bf16x8*)&WvT[(16 * cf + la) * 72 + ks * 32 + lb * 8];
                acc2[cf] = __builtin_amdgcn_mfma_f32_16x16x32_bf16(aa, bb, acc2[cf], 0, 0, 0);
            }
        }
#pragma unroll
        for (int cf = 0; cf < 4; ++cf) {
            ushort4 h;
            h.x = f2bf(acc2[cf][0] + bvv[cf]);
            h.y = f2bf(acc2[cf][1] + bvv[cf]);
            h.z = f2bf(acc2[cf][2] + bvv[cf]);
            h.w = f2bf(acc2[cf][3] + bvv[cf]);
            *(ushort4*)&vst[(16 * cf + la) * 72 + w * 16 + lb * 4] = h;   // vst[c][t_rel]
        }
        __syncthreads();

        int m = mbase + i;
        int mblk = m >> 2, mrel = m & 3;
        int cg = mrel >> 1, half = mrel & 1;
        size_t vfbase = ((((size_t)(b * 48 + mblk) * 4 + nn2) * 32 + (tt * 4 + ksr)) * 2 + cg) * 512
                      + (size_t)(lhi2 * 32 + half * 16 + d0) * 8;
        uint4 v0 = *(const uint4*)&vst[(nn2 * 16 + d0) * 72 + ksr * 16 + lhi2 * 8];
        uint4 v1 = *(const uint4*)&vst[(nn2 * 16 + d0 + 1) * 72 + ksr * 16 + lhi2 * 8];
        *(uint4*)(vf + vfbase) = v0;
        *(uint4*)(vf + vfbase + 8) = v1;

#pragma unroll
        for (int u2 = 0; u2 < 4; ++u2) xv[u2] = xv2[u2];
        xaddr = xaddr2;
    }

    if (mg == 15) {
        uint4 z4 = {0u, 0u, 0u, 0u};
#pragma unroll
        for (int pm = 190; pm < 192; ++pm) {
            int mblk = pm >> 2, mrel = pm & 3;
            int cg = mrel >> 1, half = mrel & 1;
            size_t vfbase = ((((size_t)(b * 48 + mblk) * 4 + nn2) * 32 + (tt * 4 + ksr)) * 2 + cg) * 512
                          + (size_t)(lhi2 * 32 + half * 16 + d0) * 8;
            *(uint4*)(vf + vfbase) = z4;
            *(uint4*)(vf + vfbase + 8) = z4;
        }
    }

    size_t sbase = ((size_t)(mg * 4 + b) * TDIM + t0 + r) * CDIM + seg * 16;
#pragma unroll
    for (int u2 = 0; u2 < 4; ++u2) {
        float4 o;
        o.x = xacc[u2 * 4 + 0]; o.y = xacc[u2 * 4 + 1];
        o.z = xacc[u2 * 4 + 2]; o.w = xacc[u2 * 4 + 3];
        *(float4*)(xsp + sbase + u2 * 4) = o;
    }
}

// ---------------------------------------------------------------- K1b: reduce 16 partials -> xsum; block 0 also builds wpf
// wpf[cf2][kk4][lane64][8]: GEMM2 B-frag: element = Wp[(kk*16+lhi*8+j)*64 + cf*32+l31]
__global__ __launch_bounds__(256) void k_xsum2(const float* __restrict__ xsp,
                                               const float* __restrict__ Wp,
                                               float* __restrict__ xsum,
                                               ushort_t* __restrict__ wpf) {
    int tid = threadIdx.x;
    int idx = blockIdx.x * 256 + tid;   // 131072
    float s = 0.f;
#pragma unroll
    for (int p = 0; p < 16; ++p) s += xsp[(size_t)p * 131072 + idx];
    xsum[idx] = s;

    if (blockIdx.x == 0) {
#pragma unroll
        for (int rp = 0; rp < 16; ++rp) {
            int u = rp * 256 + tid;            // 0..4095
            int cf = u >> 11, kk = (u >> 9) & 3, lf = (u >> 3) & 63, j = u & 7;
            wpf[u] = f2bf(Wp[(kk * 16 + (lf >> 5) * 8 + j) * 64 + cf * 32 + (lf & 31)]);
        }
    }
}

// ---------------------------------------------------------------- K2: weights (qt/kt + softmax), frag-order output
// wf[b][n][tq16][ks32][lane64][elem8]: row = tq*32 + l31, k = ks*16 + lhi*8 + j.
__global__ __launch_bounds__(256) void k_weights(const float* __restrict__ xsum,
                                                 const float* __restrict__ Wq,
                                                 const float* __restrict__ bq,
                                                 const float* __restrict__ Wk,
                                                 const float* __restrict__ bk,
                                                 ushort_t* __restrict__ wf,
                                                 float* __restrict__ a_out) {
    __shared__ __align__(16) float kt[512][20];
    __shared__ __align__(16) float qt[32][20];
    __shared__ __align__(16) float xs[64][68];
    __shared__ __align__(16) float wcol[64][16];
    __shared__ float kbias[16], qbias[16];
    __shared__ __align__(16) ushort_t rowbuf[32][520];

    int tid = threadIdx.x;
    int bid = blockIdx.x;        // 256 blocks
    int tcn = bid & 15;          // t-chunk (32 rows) == tq
    int n = (bid >> 4) & 3;
    int b = bid >> 6;
    int t0 = tcn * 32;

    for (int j = tid; j < 1024; j += 256) {
        int c = j >> 4, d = j & 15;
        wcol[c][d] = Wk[c * 64 + n * 16 + d];
    }
    if (tid < 16) kbias[tid] = 190.0f * bk[n * 16 + tid];
    if (tid >= 16 && tid < 32) qbias[tid - 16] = 190.0f * bq[n * 16 + tid - 16];
    __syncthreads();

    for (int ch = 0; ch < 8; ++ch) {
        for (int j = tid; j < 4096; j += 256) {
            int t = j >> 6, c = j & 63;
            xs[t][c] = xsum[((size_t)(b * 512) + (ch * 64 + t)) * 64 + c];
        }
        __syncthreads();
#pragma unroll
        for (int o = 0; o < 4; ++o) {
            int oi = o * 256 + tid;
            int t = oi >> 4, d = oi & 15;
            float s = 0.f;
#pragma unroll
            for (int c = 0; c < 64; ++c) s += xs[t][c] * wcol[c][d];
            kt[ch * 64 + t][d] = s + kbias[d];
        }
        __syncthreads();
    }

    for (int j = tid; j < 1024; j += 256) {
        int c = j >> 4, d = j & 15;
        wcol[c][d] = Wq[c * 64 + n * 16 + d];
    }
    for (int j = tid; j < 2048; j += 256) {
        int t = j >> 6, c = j & 63;
        xs[t][c] = xsum[((size_t)(b * 512) + (t0 + t)) * 64 + c];
    }
    __syncthreads();
#pragma unroll
    for (int o = 0; o < 2; ++o) {
        int oi = o * 256 + tid;
        int t = oi >> 4, d = oi & 15;
        float s = 0.f;
#pragma unroll
        for (int c = 0; c < 64; ++c) s += xs[t][c] * wcol[c][d];
        qt[t][d] = s + qbias[d];
    }
    __syncthreads();

    const float scale = 0.01813692f;  // 1/sqrt(16*190)
    int w = tid >> 6, lane = tid & 63;
    for (int rr = 0; rr < 8; ++rr) {
        int r = w * 8 + rr;
        float qreg[16];
#pragma unroll
        for (int d = 0; d < 16; ++d) qreg[d] = qt[r][d];
        float lv[8];
#pragma unroll
        for (int i = 0; i < 8; ++i) {
            int k = lane + 64 * i;
            const float* kr = &kt[k][0];
            float s = 0.f;
#pragma unroll
            for (int d = 0; d < 16; ++d) s += qreg[d] * kr[d];
            lv[i] = s * scale;
        }
        float mx = lv[0];
#pragma unroll
        for (int i = 1; i < 8; ++i) mx = fmaxf(mx, lv[i]);
#pragma unroll
        for (int off = 32; off >= 1; off >>= 1) mx = fmaxf(mx, __shfl_xor(mx, off));
        float se = 0.f;
#pragma unroll
        for (int i = 0; i < 8; ++i) { lv[i] = __expf(lv[i] - mx); se += lv[i]; }
#pragma unroll
        for (int off = 32; off >= 1; off >>= 1) se += __shfl_xor(se, off);
        float inv = 1.0f / se;

        size_t abase = ((size_t)(n * 512 + (t0 + r))) * 512;
#pragma unroll
        for (int i = 0; i < 8; ++i) {
            float wv = lv[i] * inv;
            rowbuf[r][lane + 64 * i] = f2bf(wv);
            if (b == 0) a_out[abase + lane + 64 * i] = wv;
        }
    }
    __syncthreads();

    size_t wfbase = ((size_t)((b * 4 + n) * 16 + tcn)) * 32 * 512;
#pragma unroll
    for (int p = 0; p < 8; ++p) {
        int id = p * 256 + tid;          // 0..2047
        int ks = id >> 6;
        int lf = id & 63;
        int l31 = lf & 31, lhi = lf >> 5;
        uint4 v = *(const uint4*)&rowbuf[l31][ks * 16 + lhi * 8];
        *(uint4*)(wf + wfbase + (size_t)ks * 512 + lf * 8) = v;
    }
}

// ---------------------------------------------------------------- K4: register-direct att GEMM, block=(b,8m,128t),
// 8 waves=(n, m-half), acc 128, E/O counted-vmcnt(6) pipeline. Traffic 400 MB (vs 590 R6).
__global__ __launch_bounds__(512, 2) void k_att(const ushort_t* __restrict__ wf,
                                                const ushort_t* __restrict__ vf,
                                                const ushort_t* __restrict__ wpf,
                                                const float* __restrict__ bp,
                                                float* __restrict__ out) {
    __shared__ __align__(16) ushort_t attS[32768];   // 64 KB, XOR-swizzled rows

    int tid = threadIdx.x;
    int bid0 = blockIdx.x;                     // 384 = 16 panels * 24 mq
    int bid = (bid0 & 7) * 48 + (bid0 >> 3);   // XCD x -> logical [48x, 48x+48): 2 panels, mq fastest
    int mq = bid % 24;                         // 8 m each
    int panel = bid / 24;                      // 0..15 = (b, tt)
    int tt = panel & 3;                        // 128-t tile
    int b = panel >> 2;

    int wid = tid >> 6, lane = tid & 63;
    int l31 = lane & 31, lhi = lane >> 5;
    int n = wid >> 1;        // head
    int mh = wid & 1;        // m-half: mblk = mq*2 + mh
    int mblk = mq * 2 + mh;

    // A: q = t-32-group within the 128t tile
    unsigned abase[4];
#pragma unroll
    for (int q = 0; q < 4; ++q)
        abase[q] = (unsigned)((((b * 4 + n) * 16 + tt * 4 + q) * 32) * 512 + lane * 8);
    // B: cg = col-32-group (2m x 16d each)
    unsigned bbase[2];
#pragma unroll
    for (int j = 0; j < 2; ++j)
        bbase[j] = (unsigned)(((((b * 48 + mblk) * 4 + n) * 32) * 2 + j) * 512 + lane * 8);

    f32x16 acc[4][2];
#pragma unroll
    for (int q = 0; q < 4; ++q)
#pragma unroll
        for (int j = 0; j < 2; ++j) acc[q][j] = (f32x16)(0.f);

    bf16x8 Ae[4], Be[2], Ao[4], Bo[2];

#define LOADC(A_, B_, KS) do {                                                    \
    _Pragma("unroll")                                                             \
    for (int q = 0; q < 4; ++q)                                                   \
        A_[q] = *(const bf16x8*)(wf + abase[q] + (KS) * 512);                     \
    _Pragma("unroll")                                                             \
    for (int j = 0; j < 2; ++j)                                                   \
        B_[j] = *(const bf16x8*)(vf + bbase[j] + (KS) * 1024);                    \
} while (0)

#define COMPC(A_, B_) do {                                                        \
    _Pragma("unroll")                                                             \
    for (int j = 0; j < 2; ++j)                                                   \
        _Pragma("unroll")                                                         \
        for (int q = 0; q < 4; ++q)                                               \
            acc[q][j] = __builtin_amdgcn_mfma_f32_32x32x16_bf16(A_[q], B_[j], acc[q][j], 0, 0, 0); \
} while (0)

#define VMW(N) do { asm volatile("s_waitcnt vmcnt(" #N ")" ::: "memory"); __builtin_amdgcn_sched_barrier(0); } while (0)

    LOADC(Ae, Be, 0);
    LOADC(Ao, Bo, 1);
#pragma unroll
    for (int kc = 0; kc < 30; kc += 2) {
        VMW(6);  COMPC(Ae, Be);  LOADC(Ae, Be, kc + 2);
        VMW(6);  COMPC(Ao, Bo);  LOADC(Ao, Bo, kc + 3);
    }
    VMW(6);  COMPC(Ae, Be);      // ks 30
    VMW(0);  COMPC(Ao, Bo);      // ks 31
#undef LOADC
#undef COMPC
#undef VMW

    // ---- epilogue: two 4m passes; attS[4m][128t][64c] XOR-swizzled; GEMM2 via wpf frags
    float bpv[2];
#pragma unroll
    for (int cf = 0; cf < 2; ++cf) bpv[cf] = bp[cf * 32 + l31];

    int mloc2 = wid >> 1;      // GEMM2: m row within the 4m pass
    int th2 = wid & 1;         // 64-t half

#pragma unroll
    for (int h = 0; h < 2; ++h) {
        __syncthreads();
        if (mh == h) {
            int mloc = ((l31 >> 4));           // + cg*2
            int d = l31 & 15;
#pragma unroll
            for (int cg = 0; cg < 2; ++cg)
#pragma unroll
                for (int q = 0; q < 4; ++q) {
                    f32x16 a = acc[q][cg];
                    int ml = cg * 2 + mloc;
#pragma unroll
                    for (int r = 0; r < 16; ++r) {
                        int tl = q * 32 + (r & 3) + 8 * (r >> 2) + 4 * lhi;
                        int idx = (((ml * 128 + tl) * 64) + n * 16 + d) ^ ((tl & 7) << 3);
                        attS[idx] = f2bf(a[r]);
                    }
                }
        }
        __syncthreads();

        f32x16 acc2[2][2];
#pragma unroll
        for (int q2 = 0; q2 < 2; ++q2)
#pragma unroll
            for (int cf = 0; cf < 2; ++cf) acc2[q2][cf] = (f32x16)(0.f);
#pragma unroll
        for (int kk = 0; kk < 4; ++kk) {
            bf16x8 bbf[2];
#pragma unroll
            for (int cf = 0; cf < 2; ++cf)
                bbf[cf] = *(const bf16x8*)(wpf + (cf * 4 + kk) * 512 + lane * 8);
#pragma unroll
            for (int q2 = 0; q2 < 2; ++q2) {
                int tl = th2 * 64 + q2 * 32 + l31;
                int aidx = (((mloc2 * 128 + tl) * 64) + kk * 16 + lhi * 8) ^ ((tl & 7) << 3);
                bf16x8 aa = *(const bf16x8*)(attS + aidx);
#pragma unroll
                for (int cf = 0; cf < 2; ++cf)
                    acc2[q2][cf] = __builtin_amdgcn_mfma_f32_32x32x16_bf16(aa, bbf[cf], acc2[q2][cf], 0, 0, 0);
            }
        }
        int m = mq * 8 + h * 4 + mloc2;
        if (m < 190) {
            size_t obase = ((size_t)(b * 190 + m) * 512 + tt * 128 + th2 * 64) * 64;
#pragma unroll
            for (int q2 = 0; q2 < 2; ++q2)
#pragma unroll
                for (int cf = 0; cf < 2; ++cf)
#pragma unroll
                    for (int r = 0; r < 16; ++r) {
                        int ts = q2 * 32 + (r & 3) + 8 * (r >> 2) + 4 * lhi;
                        out[obase + (size_t)ts * 64 + cf * 32 + l31] = acc2[q2][cf][r] + bpv[cf];
                    }
        }
    }
}

// ----------------------------------------------------------------
extern "C" void kernel_launch(void* const* d_in, const int* in_sizes, int n_in,
                              void* d_out, int out_size, void* d_ws, size_t ws_size,
                              hipStream_t stream) {
    const float* x  = (const float*)d_in[0];
    const float* Wq = (const float*)d_in[1];
    const float* bq = (const float*)d_in[2];
    const float* Wk = (const float*)d_in[3];
    const float* bk = (const float*)d_in[4];
    const float* Wv = (const float*)d_in[5];
    const float* bv = (const float*)d_in[6];
    const float* Wp = (const float*)d_in[7];
    const float* bp = (const float*)d_in[8];

    float* out = (float*)d_out;
    float* a_out = out + (size_t)BSZ * MDIM * TDIM * CDIM;   // 24903680

    // xsum partials in the out region (8 MB), fully overwritten by k_att later.
    float* xsp = out;

    float* xsum = (float*)d_ws;                                         // 512 KB
    ushort_t* wf = (ushort_t*)((char*)d_ws + 524288);                   // 8.39 MB
    ushort_t* vf = (ushort_t*)((char*)d_ws + 524288 + 8388608);         // 50.33 MB
    ushort_t* wpf = (ushort_t*)((char*)d_ws + 524288 + 8388608 + 50331648);  // 8 KB

    k_vproj<<<512, 256, 0, stream>>>(x, Wv, bv, vf, xsp);
    k_xsum2<<<512, 256, 0, stream>>>(xsp, Wp, xsum, wpf);
    k_weights<<<256, 256, 0, stream>>>(xsum, Wq, bq, Wk, bk, wf, a_out);
    k_att<<<384, 512, 0, stream>>>(wf, vf, wpf, bp, out);
}

// Round 13
// 120.734 us; speedup vs baseline: 1.5176x; 1.1642x over previous
//
#include <hip/hip_runtime.h>

typedef unsigned short ushort_t;
typedef __bf16 bf16x8 __attribute__((ext_vector_type(8)));
typedef float f32x4 __attribute__((ext_vector_type(4)));
typedef float f32x16 __attribute__((ext_vector_type(16)));

#define DEVI __device__ __forceinline__

constexpr int BSZ = 4;     // batch
constexpr int MDIM = 190;  // axial dim
constexpr int TDIM = 512;  // seq
constexpr int CDIM = 64;   // channels

DEVI ushort_t f2bf(float f) {
    union { float f; unsigned int u; } v; v.f = f;
    unsigned int u = v.u;
    u += 0x7FFFu + ((u >> 16) & 1u);   // round-to-nearest-even
    return (ushort_t)(u >> 16);
}

DEVI void gload16(ushort_t* ldsBase, const ushort_t* g) {
    __builtin_amdgcn_global_load_lds(
        (const __attribute__((address_space(1))) unsigned int*)g,
        (__attribute__((address_space(3))) unsigned int*)ldsBase, 16, 0, 0);
}

// ---------------------------------------------------------------- K1: fused v-projection + xsum partials
// vf[b][mblk48][n][ks32][cg2][lane64][elem8]
__global__ __launch_bounds__(256, 4) void k_vproj(const float* __restrict__ x,
                                                  const float* __restrict__ Wv,
                                                  const float* __restrict__ bv,
                                                  ushort_t* __restrict__ vf,
                                                  float* __restrict__ xsp) {
    __shared__ __align__(16) ushort_t xbf[64 * 72];
    __shared__ __align__(16) ushort_t WvT[64 * 72];
    __shared__ __align__(16) ushort_t vst[64 * 72];

    int tid = threadIdx.x;
    int bid = blockIdx.x;            // 512 = 4b * 8tt * 16mg
    int mg = bid & 15;
    int tt = (bid >> 4) & 7;
    int b = bid >> 7;
    int t0 = tt * 64;
    int mbase = mg * 12;
    int cnt = (mbase + 12 <= MDIM) ? 12 : (MDIM - mbase);   // 12 or 10

    int w = tid >> 6, lane = tid & 63;
    int la = lane & 15, lb = lane >> 4;
    int r = tid >> 2, seg = tid & 3;

    int chunk = tid >> 3, u = tid & 7;
    int ksr = chunk >> 3;
    int nn2 = (chunk >> 1) & 3;
    int lhi2 = chunk & 1;
    int d0 = u * 2;

#pragma unroll
    for (int rep = 0; rep < 16; ++rep) {
        int j = rep * 256 + tid;
        int ci = j >> 6, co = j & 63;
        WvT[co * 72 + ci] = f2bf(Wv[j]);
    }
    float bvv[4];
#pragma unroll
    for (int cf = 0; cf < 4; ++cf) bvv[cf] = bv[16 * cf + la];

    float xacc[16];
#pragma unroll
    for (int u2 = 0; u2 < 16; ++u2) xacc[u2] = 0.f;

    const size_t mstride = (size_t)TDIM * CDIM;  // 32768
    size_t xaddr = ((size_t)(b * MDIM + mbase) * TDIM + t0 + r) * CDIM + seg * 16;

    float4 xv[4];
#pragma unroll
    for (int u2 = 0; u2 < 4; ++u2) xv[u2] = *(const float4*)(x + xaddr + u2 * 4);

    f32x4 zz = {0.f, 0.f, 0.f, 0.f};

    for (int i = 0; i < cnt; ++i) {
#pragma unroll
        for (int u2 = 0; u2 < 4; ++u2) {
            xacc[u2 * 4 + 0] += xv[u2].x;
            xacc[u2 * 4 + 1] += xv[u2].y;
            xacc[u2 * 4 + 2] += xv[u2].z;
            xacc[u2 * 4 + 3] += xv[u2].w;
            ushort4 h;
            h.x = f2bf(xv[u2].x); h.y = f2bf(xv[u2].y);
            h.z = f2bf(xv[u2].z); h.w = f2bf(xv[u2].w);
            *(ushort4*)&xbf[r * 72 + seg * 16 + u2 * 4] = h;
        }
        __syncthreads();

        int inext = (i + 1 < cnt) ? (i + 1) : i;
        size_t xaddr2 = xaddr + (size_t)(inext - i) * mstride;
        float4 xv2[4];
#pragma unroll
        for (int u2 = 0; u2 < 4; ++u2) xv2[u2] = *(const float4*)(x + xaddr2 + u2 * 4);

        f32x4 acc2[4];
#pragma unroll
        for (int cf = 0; cf < 4; ++cf) acc2[cf] = zz;
#pragma unroll
        for (int ks = 0; ks < 2; ++ks) {
            bf16x8 aa = *(const bf16x8*)&xbf[(w * 16 + la) * 72 + ks * 32 + lb * 8];
#pragma unroll
            for (int cf = 0; cf < 4; ++cf) {
                bf16x8 bb = *(const bf16x8*)&WvT[(16 * cf + la) * 72 + ks * 32 + lb * 8];
                acc2[cf] = __builtin_amdgcn_mfma_f32_16x16x32_bf16(aa, bb, acc2[cf], 0, 0, 0);
            }
        }
#pragma unroll
        for (int cf = 0; cf < 4; ++cf) {
            ushort4 h;
            h.x = f2bf(acc2[cf][0] + bvv[cf]);
            h.y = f2bf(acc2[cf][1] + bvv[cf]);
            h.z = f2bf(acc2[cf][2] + bvv[cf]);
            h.w = f2bf(acc2[cf][3] + bvv[cf]);
            *(ushort4*)&vst[(16 * cf + la) * 72 + w * 16 + lb * 4] = h;   // vst[c][t_rel]
        }
        __syncthreads();

        int m = mbase + i;
        int mblk = m >> 2, mrel = m & 3;
        int cg = mrel >> 1, half = mrel & 1;
        size_t vfbase = ((((size_t)(b * 48 + mblk) * 4 + nn2) * 32 + (tt * 4 + ksr)) * 2 + cg) * 512
                      + (size_t)(lhi2 * 32 + half * 16 + d0) * 8;
        uint4 v0 = *(const uint4*)&vst[(nn2 * 16 + d0) * 72 + ksr * 16 + lhi2 * 8];
        uint4 v1 = *(const uint4*)&vst[(nn2 * 16 + d0 + 1) * 72 + ksr * 16 + lhi2 * 8];
        *(uint4*)(vf + vfbase) = v0;
        *(uint4*)(vf + vfbase + 8) = v1;

#pragma unroll
        for (int u2 = 0; u2 < 4; ++u2) xv[u2] = xv2[u2];
        xaddr = xaddr2;
    }

    if (mg == 15) {
        uint4 z4 = {0u, 0u, 0u, 0u};
#pragma unroll
        for (int pm = 190; pm < 192; ++pm) {
            int mblk = pm >> 2, mrel = pm & 3;
            int cg = mrel >> 1, half = mrel & 1;
            size_t vfbase = ((((size_t)(b * 48 + mblk) * 4 + nn2) * 32 + (tt * 4 + ksr)) * 2 + cg) * 512
                          + (size_t)(lhi2 * 32 + half * 16 + d0) * 8;
            *(uint4*)(vf + vfbase) = z4;
            *(uint4*)(vf + vfbase + 8) = z4;
        }
    }

    size_t sbase = ((size_t)(mg * 4 + b) * TDIM + t0 + r) * CDIM + seg * 16;
#pragma unroll
    for (int u2 = 0; u2 < 4; ++u2) {
        float4 o;
        o.x = xacc[u2 * 4 + 0]; o.y = xacc[u2 * 4 + 1];
        o.z = xacc[u2 * 4 + 2]; o.w = xacc[u2 * 4 + 3];
        *(float4*)(xsp + sbase + u2 * 4) = o;
    }
}

// ---------------------------------------------------------------- K1b: reduce 16 partials -> xsum; block 0 builds wpf
__global__ __launch_bounds__(256) void k_xsum2(const float* __restrict__ xsp,
                                               const float* __restrict__ Wp,
                                               float* __restrict__ xsum,
                                               ushort_t* __restrict__ wpf) {
    int tid = threadIdx.x;
    int idx = blockIdx.x * 256 + tid;   // 131072
    float s = 0.f;
#pragma unroll
    for (int p = 0; p < 16; ++p) s += xsp[(size_t)p * 131072 + idx];
    xsum[idx] = s;

    if (blockIdx.x == 0) {
#pragma unroll
        for (int rp = 0; rp < 16; ++rp) {
            int u = rp * 256 + tid;            // 0..4095
            int cf = u >> 11, kk = (u >> 9) & 3, lf = (u >> 3) & 63, j = u & 7;
            wpf[u] = f2bf(Wp[(kk * 16 + (lf >> 5) * 8 + j) * 64 + cf * 32 + (lf & 31)]);
        }
    }
}

// ---------------------------------------------------------------- K2: weights (qt/kt + softmax), frag-order output
__global__ __launch_bounds__(256) void k_weights(const float* __restrict__ xsum,
                                                 const float* __restrict__ Wq,
                                                 const float* __restrict__ bq,
                                                 const float* __restrict__ Wk,
                                                 const float* __restrict__ bk,
                                                 ushort_t* __restrict__ wf,
                                                 float* __restrict__ a_out) {
    __shared__ __align__(16) float kt[512][20];
    __shared__ __align__(16) float qt[32][20];
    __shared__ __align__(16) float xs[64][68];
    __shared__ __align__(16) float wcol[64][16];
    __shared__ float kbias[16], qbias[16];
    __shared__ __align__(16) ushort_t rowbuf[32][520];

    int tid = threadIdx.x;
    int bid = blockIdx.x;        // 256 blocks
    int tcn = bid & 15;          // t-chunk (32 rows) == tq
    int n = (bid >> 4) & 3;
    int b = bid >> 6;
    int t0 = tcn * 32;

    for (int j = tid; j < 1024; j += 256) {
        int c = j >> 4, d = j & 15;
        wcol[c][d] = Wk[c * 64 + n * 16 + d];
    }
    if (tid < 16) kbias[tid] = 190.0f * bk[n * 16 + tid];
    if (tid >= 16 && tid < 32) qbias[tid - 16] = 190.0f * bq[n * 16 + tid - 16];
    __syncthreads();

    for (int ch = 0; ch < 8; ++ch) {
        for (int j = tid; j < 4096; j += 256) {
            int t = j >> 6, c = j & 63;
            xs[t][c] = xsum[((size_t)(b * 512) + (ch * 64 + t)) * 64 + c];
        }
        __syncthreads();
#pragma unroll
        for (int o = 0; o < 4; ++o) {
            int oi = o * 256 + tid;
            int t = oi >> 4, d = oi & 15;
            float s = 0.f;
#pragma unroll
            for (int c = 0; c < 64; ++c) s += xs[t][c] * wcol[c][d];
            kt[ch * 64 + t][d] = s + kbias[d];
        }
        __syncthreads();
    }

    for (int j = tid; j < 1024; j += 256) {
        int c = j >> 4, d = j & 15;
        wcol[c][d] = Wq[c * 64 + n * 16 + d];
    }
    for (int j = tid; j < 2048; j += 256) {
        int t = j >> 6, c = j & 63;
        xs[t][c] = xsum[((size_t)(b * 512) + (t0 + t)) * 64 + c];
    }
    __syncthreads();
#pragma unroll
    for (int o = 0; o < 2; ++o) {
        int oi = o * 256 + tid;
        int t = oi >> 4, d = oi & 15;
        float s = 0.f;
#pragma unroll
        for (int c = 0; c < 64; ++c) s += xs[t][c] * wcol[c][d];
        qt[t][d] = s + qbias[d];
    }
    __syncthreads();

    const float scale = 0.01813692f;  // 1/sqrt(16*190)
    int w = tid >> 6, lane = tid & 63;
    for (int rr = 0; rr < 8; ++rr) {
        int r = w * 8 + rr;
        float qreg[16];
#pragma unroll
        for (int d = 0; d < 16; ++d) qreg[d] = qt[r][d];
        float lv[8];
#pragma unroll
        for (int i = 0; i < 8; ++i) {
            int k = lane + 64 * i;
            const float* kr = &kt[k][0];
            float s = 0.f;
#pragma unroll
            for (int d = 0; d < 16; ++d) s += qreg[d] * kr[d];
            lv[i] = s * scale;
        }
        float mx = lv[0];
#pragma unroll
        for (int i = 1; i < 8; ++i) mx = fmaxf(mx, lv[i]);
#pragma unroll
        for (int off = 32; off >= 1; off >>= 1) mx = fmaxf(mx, __shfl_xor(mx, off));
        float se = 0.f;
#pragma unroll
        for (int i = 0; i < 8; ++i) { lv[i] = __expf(lv[i] - mx); se += lv[i]; }
#pragma unroll
        for (int off = 32; off >= 1; off >>= 1) se += __shfl_xor(se, off);
        float inv = 1.0f / se;

        size_t abase = ((size_t)(n * 512 + (t0 + r))) * 512;
#pragma unroll
        for (int i = 0; i < 8; ++i) {
            float wv = lv[i] * inv;
            rowbuf[r][lane + 64 * i] = f2bf(wv);
            if (b == 0) a_out[abase + lane + 64 * i] = wv;
        }
    }
    __syncthreads();

    size_t wfbase = ((size_t)((b * 4 + n) * 16 + tcn)) * 32 * 512;
#pragma unroll
    for (int p = 0; p < 8; ++p) {
        int id = p * 256 + tid;          // 0..2047
        int ks = id >> 6;
        int lf = id & 63;
        int l31 = lf & 31, lhi = lf >> 5;
        uint4 v = *(const uint4*)&rowbuf[l31][ks * 16 + lhi * 8];
        *(uint4*)(wf + wfbase + (size_t)ks * 512 + lf * 8) = v;
    }
}

// ---------------------------------------------------------------- K4: latency-engineered att GEMM.
// Block = (b, tt64, mq of 4m); 4 waves = 4 heads. Wave tile [64t x 64c].
// V -> wave-private LDS slices via global_load_lds, 3 slots, issued 2 phases ahead (no barriers).
// W -> register-direct (L2-hot), 1 phase ahead. vmcnt(4)/phase retires exactly {V(p), W(p)}.
__global__ __launch_bounds__(256, 3) void k_att(const ushort_t* __restrict__ wf,
                                                const ushort_t* __restrict__ vf,
                                                const ushort_t* __restrict__ wpf,
                                                const float* __restrict__ bp,
                                                float* __restrict__ out) {
    __shared__ __align__(16) ushort_t lds[24576];   // 48KB: vbuf[4][3][2][2][512]; epilogue attS (16K) reuses

    int tid = threadIdx.x;
    int bid0 = blockIdx.x;                      // 1536 = 32 panels(b,tt) * 48 mq
    int bid = (bid0 & 7) * 192 + (bid0 >> 3);   // XCD x -> logical [192x,192x+192): 4 panels, tt-fastest order inside
    int tt = bid & 7;                           // 64-t tile (fastest: consecutive blocks share V slice)
    int mq = (bid >> 3) % 48;                   // 4 m each
    int b = bid / 384;

    int w = tid >> 6, lane = tid & 63;
    int l31 = lane & 31, lhi = lane >> 5;
    int n = w;   // head per wave

    // A (W) bases: tq = tt*2 + q
    unsigned abase[2];
#pragma unroll
    for (int q = 0; q < 2; ++q)
        abase[q] = (unsigned)((((b * 4 + n) * 16 + tt * 2 + q) * 32) * 512 + lane * 8);
    // V source base (per-lane): chunk (ks,cg) at + ks*1024 + cg*512
    unsigned vbase = (unsigned)(((b * 48 + mq) * 4 + n) * 32768 + lane * 8);
    // wave's LDS region
    int nbase = n * 6144;
    ushort_t* vwave = lds + nbase;

    f32x16 acc[2][2];
#pragma unroll
    for (int q = 0; q < 2; ++q)
#pragma unroll
        for (int j = 0; j < 2; ++j) acc[q][j] = (f32x16)(0.f);

    bf16x8 We[2][2], Wo[2][2];

#define WLOAD(W_, P) do {                                                         \
    _Pragma("unroll")                                                             \
    for (int kk = 0; kk < 2; ++kk)                                                \
        _Pragma("unroll")                                                         \
        for (int q = 0; q < 2; ++q)                                               \
            W_[kk][q] = *(const bf16x8*)(wf + abase[q] + ((P) * 2 + kk) * 512);   \
} while (0)

#define VLOAD(P) do {                                                             \
    _Pragma("unroll")                                                             \
    for (int kk = 0; kk < 2; ++kk)                                                \
        _Pragma("unroll")                                                         \
        for (int cg = 0; cg < 2; ++cg)                                            \
            gload16(vwave + ((P) % 3) * 2048 + kk * 1024 + cg * 512,              \
                    vf + vbase + ((P) * 2 + kk) * 1024 + cg * 512);               \
} while (0)

#define SB __builtin_amdgcn_sched_barrier(0)
#define VMW4 do { asm volatile("s_waitcnt vmcnt(4)" ::: "memory"); SB; } while (0)
#define VMW0 do { asm volatile("s_waitcnt vmcnt(0)" ::: "memory"); SB; } while (0)

#define MM(W_, P) do {                                                            \
    bf16x8 Bv[2][2];                                                              \
    _Pragma("unroll")                                                             \
    for (int kk = 0; kk < 2; ++kk)                                                \
        _Pragma("unroll")                                                         \
        for (int cg = 0; cg < 2; ++cg)                                            \
            Bv[kk][cg] = *(const bf16x8*)(vwave + ((P) % 3) * 2048 + kk * 1024 + cg * 512 + lane * 8); \
    SB;                                                                           \
    if ((P) < 15) { if ((P) & 1) WLOAD(We, (P) + 1); else WLOAD(Wo, (P) + 1); }   \
    SB;                                                                           \
    if ((P) < 14) VLOAD((P) + 2);                                                 \
    SB;                                                                           \
    _Pragma("unroll")                                                             \
    for (int kk = 0; kk < 2; ++kk)                                                \
        _Pragma("unroll")                                                         \
        for (int q = 0; q < 2; ++q)                                               \
            _Pragma("unroll")                                                     \
            for (int cg = 0; cg < 2; ++cg)                                        \
                acc[q][cg] = __builtin_amdgcn_mfma_f32_32x32x16_bf16(W_[kk][q], Bv[kk][cg], acc[q][cg], 0, 0, 0); \
} while (0)

    // prologue: W0 first (oldest), then V0, V1 -> queue [W0, V0, V1] = 12
    WLOAD(We, 0); SB;
    VLOAD(0); SB;
    VLOAD(1); SB;

    VMW4; MM(We, 0);   // wait drains W0+V0 (leaves V1 + newly issued)
    VMW4; MM(Wo, 1);
    VMW4; MM(We, 2);
    VMW4; MM(Wo, 3);
    VMW4; MM(We, 4);
    VMW4; MM(Wo, 5);
    VMW4; MM(We, 6);
    VMW4; MM(Wo, 7);
    VMW4; MM(We, 8);
    VMW4; MM(Wo, 9);
    VMW4; MM(We, 10);
    VMW4; MM(Wo, 11);
    VMW4; MM(We, 12);
    VMW4; MM(Wo, 13);
    VMW4; MM(We, 14);
    VMW0; MM(Wo, 15);

#undef WLOAD
#undef VLOAD
#undef VMW4
#undef VMW0
#undef MM
#undef SB

    // ---- epilogue: attS[4m][64t][64c] (XOR-swizzled) in reused LDS; fused GEMM2 via wpf
    float bpv[2];
#pragma unroll
    for (int cf = 0; cf < 2; ++cf) bpv[cf] = bp[cf * 32 + l31];

    __syncthreads();
    {
        int d = l31 & 15;
        int mlh = l31 >> 4;
#pragma unroll
        for (int cg = 0; cg < 2; ++cg)
#pragma unroll
            for (int q = 0; q < 2; ++q) {
                f32x16 a = acc[q][cg];
                int ml = cg * 2 + mlh;
#pragma unroll
                for (int r = 0; r < 16; ++r) {
                    int tl = q * 32 + (r & 3) + 8 * (r >> 2) + 4 * lhi;
                    lds[(((ml * 64 + tl) * 64) + n * 16 + d) ^ ((tl & 7) << 3)] = f2bf(a[r]);
                }
            }
    }
    __syncthreads();

    // GEMM2: wave w handles m = mq*4 + w; out [64t x 64c]
    f32x16 acc2[2][2];
#pragma unroll
    for (int q2 = 0; q2 < 2; ++q2)
#pragma unroll
        for (int cf = 0; cf < 2; ++cf) acc2[q2][cf] = (f32x16)(0.f);
#pragma unroll
    for (int kk = 0; kk < 4; ++kk) {
        bf16x8 bbf[2];
#pragma unroll
        for (int cf = 0; cf < 2; ++cf)
            bbf[cf] = *(const bf16x8*)(wpf + (cf * 4 + kk) * 512 + lane * 8);
#pragma unroll
        for (int q2 = 0; q2 < 2; ++q2) {
            int tl = q2 * 32 + l31;
            int aoff = (((w * 64 + tl) * 64) + kk * 16 + lhi * 8) ^ ((tl & 7) << 3);
            bf16x8 aa = *(const bf16x8*)(lds + aoff);
#pragma unroll
            for (int cf = 0; cf < 2; ++cf)
                acc2[q2][cf] = __builtin_amdgcn_mfma_f32_32x32x16_bf16(aa, bbf[cf], acc2[q2][cf], 0, 0, 0);
        }
    }
    int m = mq * 4 + w;
    if (m < 190) {
        size_t obase = ((size_t)(b * 190 + m) * 512 + tt * 64) * 64;
#pragma unroll
        for (int q2 = 0; q2 < 2; ++q2)
#pragma unroll
            for (int cf = 0; cf < 2; ++cf)
#pragma unroll
                for (int r = 0; r < 16; ++r) {
                    int ts = q2 * 32 + (r & 3) + 8 * (r >> 2) + 4 * lhi;
                    out[obase + (size_t)ts * 64 + cf * 32 + l31] = acc2[q2][cf][r] + bpv[cf];
                }
    }
}

// ----------------------------------------------------------------
extern "C" void kernel_launch(void* const* d_in, const int* in_sizes, int n_in,
                              void* d_out, int out_size, void* d_ws, size_t ws_size,
                              hipStream_t stream) {
    const float* x  = (const float*)d_in[0];
    const float* Wq = (const float*)d_in[1];
    const float* bq = (const float*)d_in[2];
    const float* Wk = (const float*)d_in[3];
    const float* bk = (const float*)d_in[4];
    const float* Wv = (const float*)d_in[5];
    const float* bv = (const float*)d_in[6];
    const float* Wp = (const float*)d_in[7];
    const float* bp = (const float*)d_in[8];

    float* out = (float*)d_out;
    float* a_out = out + (size_t)BSZ * MDIM * TDIM * CDIM;   // 24903680

    // xsum partials in the out region (8 MB), fully overwritten by k_att later.
    float* xsp = out;

    float* xsum = (float*)d_ws;                                         // 512 KB
    ushort_t* wf = (ushort_t*)((char*)d_ws + 524288);                   // 8.39 MB
    ushort_t* vf = (ushort_t*)((char*)d_ws + 524288 + 8388608);         // 50.33 MB
    ushort_t* wpf = (ushort_t*)((char*)d_ws + 524288 + 8388608 + 50331648);  // 8 KB

    k_vproj<<<512, 256, 0, stream>>>(x, Wv, bv, vf, xsp);
    k_xsum2<<<512, 256, 0, stream>>>(xsp, Wp, xsum, wpf);
    k_weights<<<256, 256, 0, stream>>>(xsum, Wq, bq, Wk, bk, wf, a_out);
    k_att<<<1536, 256, 0, stream>>>(wf, vf, wpf, bp, out);
}